// Round 2
// baseline (175.936 us; speedup 1.0000x reference)
//
#include <hip/hip_runtime.h>
#include <hip/hip_bf16.h>
#include <cstdint>

// LSTM cell: g[g,b,n] = sum_k A[b,k] * Wcat[g,k,n],  A = [x | h]  (K = 2048)
// i,f,o = sigmoid(g0,1,2), u = tanh(g3), c_t = i*u + f*c, h_t = o*tanh(c_t)
// bf16 MFMA GEMM (no fp32 MFMA on CDNA4), fused epilogue.
// Round 2: counted-vmcnt deep pipeline (T3+T4): triple-buffered LDS,
// stage tile t+2 while computing t, s_waitcnt vmcnt(6) (never 0 in loop).

#define LDS_SLOT  49152     // A 16KB + B 32KB
#define LDS_TOTAL 147456    // 3 slots

typedef __attribute__((ext_vector_type(8))) short bf16x8;   // 8 bf16 = 4 VGPR
typedef __attribute__((ext_vector_type(4))) float f32x4;
typedef __attribute__((ext_vector_type(4))) unsigned int u32x4;

static __device__ __forceinline__ unsigned short f2bf(float f) {
  union { float f; unsigned int u; } v; v.f = f;
  unsigned int u = v.u;
  unsigned int r = (u + 0x7FFFu + ((u >> 16) & 1u)) >> 16;  // RTN-even
  return (unsigned short)r;
}

static __device__ __forceinline__ void load16(const void* gp, void* lp) {
  __builtin_amdgcn_global_load_lds(
      (const __attribute__((address_space(1))) void*)gp,
      (__attribute__((address_space(3))) void*)lp, 16, 0, 0);
}

static __device__ __forceinline__ float sigmoid_f(float x) {
  return 1.0f / (1.0f + __expf(-x));
}
static __device__ __forceinline__ float tanh_f(float x) {
  float e = __expf(-2.0f * fabsf(x));
  float r = (1.0f - e) / (1.0f + e);
  return copysignf(r, x);
}

// ---- prep 1: pack A = [x | h] as bf16 [8192][2048] ----
__global__ __launch_bounds__(256) void pack_a_kernel(
    const float* __restrict__ x, const float* __restrict__ h,
    unsigned short* __restrict__ Apack) {
  int t = blockIdx.x * 256 + threadIdx.x;
  size_t base = (size_t)t * 8;
  int b = (int)(base >> 11);
  int k = (int)(base & 2047);
  const float* src = (k < 1024) ? (x + (size_t)b * 1024 + k)
                                : (h + (size_t)b * 1024 + (k - 1024));
  float4 v0 = ((const float4*)src)[0];
  float4 v1 = ((const float4*)src)[1];
  union { unsigned short s[8]; u32x4 v; } o;
  o.s[0] = f2bf(v0.x); o.s[1] = f2bf(v0.y); o.s[2] = f2bf(v0.z); o.s[3] = f2bf(v0.w);
  o.s[4] = f2bf(v1.x); o.s[5] = f2bf(v1.y); o.s[6] = f2bf(v1.z); o.s[7] = f2bf(v1.w);
  *(u32x4*)(Apack + base) = o.v;
}

// ---- prep 2: Wt[g][n][k] = bf16( k<1024 ? Wx[g][k][n] : Wh[g][k-1024][n] ) ----
__global__ __launch_bounds__(256) void prep_w_kernel(
    const float* __restrict__ Wx, const float* __restrict__ Wh,
    unsigned short* __restrict__ Wt) {
  __shared__ float tile[32][33];
  int bid = blockIdx.x;
  int g = bid >> 11;
  int rem = bid & 2047;
  int kt = rem >> 5;
  int nt = rem & 31;
  int k0 = kt * 32, n0 = nt * 32;
  int tx = threadIdx.x & 31, ty = threadIdx.x >> 5;
  const float* Wsrc;
  int ks;
  if (k0 < 1024) { Wsrc = Wx + (size_t)g * 1048576; ks = k0; }
  else           { Wsrc = Wh + (size_t)g * 1048576; ks = k0 - 1024; }
  #pragma unroll
  for (int s = 0; s < 4; ++s) {
    int r = ty + s * 8;
    tile[r][tx] = Wsrc[(size_t)(ks + r) * 1024 + n0 + tx];
  }
  __syncthreads();
  #pragma unroll
  for (int s = 0; s < 4; ++s) {
    int r = ty + s * 8;
    Wt[(size_t)((g << 10) + n0 + r) * 2048 + k0 + tx] = f2bf(tile[tx][r]);
  }
}

// ---- main: fused 4-gate GEMM + LSTM epilogue, deep-pipelined ----
// Block: 512 thr = 8 waves (2M x 4N). Tile BM=128, 64 n-cols x 4 gates, BK=64.
// Wave (wr,wc): rows [m0+wr*64, +64), cols gate g, n [n0+wc*16, +16) all g.
// LDS: 3 slots x (A[128][64] 16KB + B[4][64][64] 32KB). Stage t+2 during t.
__global__ __launch_bounds__(512, 2) void lstm_gemm_kernel(
    const unsigned short* __restrict__ Apack,   // [8192][2048] bf16
    const unsigned short* __restrict__ Wt,      // [4][1024][2048] bf16 (B^T)
    const float* __restrict__ cprev,
    float* __restrict__ out) {
  extern __shared__ char lds[];
  const int tid = threadIdx.x;
  const int l = tid & 63;
  const int w = tid >> 6;
  const int wr = w >> 2;               // 0..1
  const int wc = w & 3;                // 0..3
  const int bid = blockIdx.x;
  const int mt = bid >> 4;             // 64 m-tiles
  const int nt = bid & 15;             // 16 n-tiles
  const int m0 = mt << 7;
  const int n0 = nt << 6;

  f32x4 acc[4][4];                     // [m-frag][gate]
  #pragma unroll
  for (int mf = 0; mf < 4; ++mf)
    #pragma unroll
    for (int g = 0; g < 4; ++g) acc[mf][g] = (f32x4)0.0f;

  // Stage K-tile t into slot. Linear LDS dest (global_load_lds constraint),
  // inverse-XOR-swizzled GLOBAL source; ds_reads apply the same XOR.
  auto stage = [&](int slot, int t) {
    const int k0 = t << 6;
    char* base = lds + slot * LDS_SLOT;
    #pragma unroll
    for (int j = 0; j < 2; ++j) {                 // A: [128][64] bf16, 128B rows
      int c = j * 512 + tid;
      int Dd = c << 4;
      int row = Dd >> 7;
      int kbs = (Dd & 127) ^ ((row & 7) << 4);
      const unsigned short* gp = Apack + (size_t)(m0 + row) * 2048 + k0 + (kbs >> 1);
      load16(gp, base + ((c & ~63) << 4));
    }
    #pragma unroll
    for (int g = 0; g < 4; ++g) {                 // B: per gate [64][64] bf16
      int Dd = tid << 4;
      int row = Dd >> 7;                          // 0..63
      int kbs = (Dd & 127) ^ ((row & 7) << 4);
      const unsigned short* gp =
          Wt + (size_t)((g << 10) + n0 + row) * 2048 + k0 + (kbs >> 1);
      load16(gp, base + 16384 + (g << 13) + ((tid & ~63) << 4));
    }
  };

  const int lr = l & 15;
  const int kgrp = (l >> 4) << 4;      // 0/16/32/48 byte k-group
  const int arow = wr * 64 + lr;       // + mf*16; (row&7)==(lr&7) for all frags
  const int brow = wc * 16 + lr;
  const int sxr = (lr & 7) << 4;       // XOR swizzle, same for A and B reads

  stage(0, 0);
  stage(1, 1);

  int sc = 0;                          // slot of current tile
  #pragma unroll 1
  for (int t = 0; t < 32; ++t) {
    // Counted wait: tile t's 6 loads landed; tile t+1's 6 stay in flight.
    if (t < 31) asm volatile("s_waitcnt vmcnt(6)" ::: "memory");
    else        asm volatile("s_waitcnt vmcnt(0)" ::: "memory");
    __builtin_amdgcn_sched_barrier(0);
    __builtin_amdgcn_s_barrier();      // all waves landed tile t; t-1 reads done
    __builtin_amdgcn_sched_barrier(0);
    if (t + 2 < 32) {                  // stage t+2 into slot of t-1 (now free)
      int sn = sc + 2; if (sn >= 3) sn -= 3;
      stage(sn, t + 2);
    }
    __builtin_amdgcn_sched_barrier(0); // keep stage issue ahead of ds_reads
    const char* Ab = lds + sc * LDS_SLOT;
    const char* Bb = Ab + 16384;
    #pragma unroll
    for (int kk = 0; kk < 2; ++kk) {
      const int kbs = (kk * 64 + kgrp) ^ sxr;
      bf16x8 a0 = *(const bf16x8*)(Ab + (arow     ) * 128 + kbs);
      bf16x8 a1 = *(const bf16x8*)(Ab + (arow + 16) * 128 + kbs);
      bf16x8 a2 = *(const bf16x8*)(Ab + (arow + 32) * 128 + kbs);
      bf16x8 a3 = *(const bf16x8*)(Ab + (arow + 48) * 128 + kbs);
      bf16x8 b0 = *(const bf16x8*)(Bb +         brow * 128 + kbs);
      bf16x8 b1 = *(const bf16x8*)(Bb +  8192 + brow * 128 + kbs);
      bf16x8 b2 = *(const bf16x8*)(Bb + 16384 + brow * 128 + kbs);
      bf16x8 b3 = *(const bf16x8*)(Bb + 24576 + brow * 128 + kbs);
      __builtin_amdgcn_s_setprio(1);
      acc[0][0] = __builtin_amdgcn_mfma_f32_16x16x32_bf16(a0, b0, acc[0][0], 0, 0, 0);
      acc[0][1] = __builtin_amdgcn_mfma_f32_16x16x32_bf16(a0, b1, acc[0][1], 0, 0, 0);
      acc[0][2] = __builtin_amdgcn_mfma_f32_16x16x32_bf16(a0, b2, acc[0][2], 0, 0, 0);
      acc[0][3] = __builtin_amdgcn_mfma_f32_16x16x32_bf16(a0, b3, acc[0][3], 0, 0, 0);
      acc[1][0] = __builtin_amdgcn_mfma_f32_16x16x32_bf16(a1, b0, acc[1][0], 0, 0, 0);
      acc[1][1] = __builtin_amdgcn_mfma_f32_16x16x32_bf16(a1, b1, acc[1][1], 0, 0, 0);
      acc[1][2] = __builtin_amdgcn_mfma_f32_16x16x32_bf16(a1, b2, acc[1][2], 0, 0, 0);
      acc[1][3] = __builtin_amdgcn_mfma_f32_16x16x32_bf16(a1, b3, acc[1][3], 0, 0, 0);
      acc[2][0] = __builtin_amdgcn_mfma_f32_16x16x32_bf16(a2, b0, acc[2][0], 0, 0, 0);
      acc[2][1] = __builtin_amdgcn_mfma_f32_16x16x32_bf16(a2, b1, acc[2][1], 0, 0, 0);
      acc[2][2] = __builtin_amdgcn_mfma_f32_16x16x32_bf16(a2, b2, acc[2][2], 0, 0, 0);
      acc[2][3] = __builtin_amdgcn_mfma_f32_16x16x32_bf16(a2, b3, acc[2][3], 0, 0, 0);
      acc[3][0] = __builtin_amdgcn_mfma_f32_16x16x32_bf16(a3, b0, acc[3][0], 0, 0, 0);
      acc[3][1] = __builtin_amdgcn_mfma_f32_16x16x32_bf16(a3, b1, acc[3][1], 0, 0, 0);
      acc[3][2] = __builtin_amdgcn_mfma_f32_16x16x32_bf16(a3, b2, acc[3][2], 0, 0, 0);
      acc[3][3] = __builtin_amdgcn_mfma_f32_16x16x32_bf16(a3, b3, acc[3][3], 0, 0, 0);
      __builtin_amdgcn_s_setprio(0);
      __builtin_amdgcn_sched_barrier(0);
    }
    sc += 1; if (sc >= 3) sc -= 3;
  }

  // Epilogue: C/D layout col = lane&15, row = (lane>>4)*4 + reg  [m89]
  const int q = (l >> 4) << 2;
  const int col = n0 + wc * 16 + lr;
  #pragma unroll
  for (int mf = 0; mf < 4; ++mf) {
    #pragma unroll
    for (int j = 0; j < 4; ++j) {
      int row = m0 + wr * 64 + mf * 16 + q + j;
      float gi = acc[mf][0][j];
      float gf = acc[mf][1][j];
      float go = acc[mf][2][j];
      float gu = acc[mf][3][j];
      float i_ = sigmoid_f(gi);
      float f_ = sigmoid_f(gf);
      float o_ = sigmoid_f(go);
      float u_ = tanh_f(gu);
      size_t idx = (size_t)row * 1024 + col;
      float ct = i_ * u_ + f_ * cprev[idx];
      float ht = o_ * tanh_f(ct);
      out[idx] = ht;                   // h_t
      out[8388608 + idx] = ct;         // c_t
    }
  }
}

extern "C" void kernel_launch(void* const* d_in, const int* in_sizes, int n_in,
                              void* d_out, int out_size, void* d_ws, size_t ws_size,
                              hipStream_t stream) {
  const float* x  = (const float*)d_in[0];
  const float* h  = (const float*)d_in[1];
  const float* c  = (const float*)d_in[2];
  const float* Wx = (const float*)d_in[3];
  const float* Wh = (const float*)d_in[4];
  float* out = (float*)d_out;

  unsigned short* Apack = (unsigned short*)d_ws;                  // 33,554,432 B
  unsigned short* Wt = (unsigned short*)((char*)d_ws + 33554432); // 16,777,216 B

  // >64KB dynamic LDS needs the attribute raised (idempotent, capture-safe:
  // not a stream operation).
  hipFuncSetAttribute((const void*)lstm_gemm_kernel,
                      hipFuncAttributeMaxDynamicSharedMemorySize, LDS_TOTAL);

  pack_a_kernel<<<8192, 256, 0, stream>>>(x, h, Apack);
  prep_w_kernel<<<8192, 256, 0, stream>>>(Wx, Wh, Wt);
  lstm_gemm_kernel<<<dim3(1024), dim3(512), LDS_TOTAL, stream>>>(Apack, Wt, c, out);
}